// Round 11
// baseline (327.280 us; speedup 1.0000x reference)
//
#include <hip/hip_runtime.h>

#define N_NODES 50000
#define N_EDGES 800000

typedef __attribute__((ext_vector_type(8))) short short8;
typedef __attribute__((ext_vector_type(4))) float floatx4;

// float -> bf16 bits, round-to-nearest-even
static __device__ __forceinline__ unsigned short f2b(float f) {
    unsigned int u = __float_as_uint(f);
    unsigned int r = u + 0x7fffu + ((u >> 16) & 1u);
    return (unsigned short)(r >> 16);
}
static __device__ __forceinline__ unsigned int pk(float a, float b) {
    return (unsigned)f2b(a) | ((unsigned)f2b(b) << 16);
}
static __device__ __forceinline__ float blo(unsigned int u) {
    return __uint_as_float(u << 16);
}
static __device__ __forceinline__ float bhi(unsigned int u) {
    return __uint_as_float(u & 0xffff0000u);
}

// ---------------------------------------------------------------------------
// CSR build. hist_rank: histogram + per-edge rank in one pass; fill is then
// atomic-free. (R9 lesson: grid.sync() costs ~100us/barrier — keep separate
// dispatches.)
// ---------------------------------------------------------------------------
__global__ void hist_rank_kernel(const int* __restrict__ dst,
                                 int* __restrict__ deg, int* __restrict__ rank,
                                 int n) {
    int i = blockIdx.x * blockDim.x + threadIdx.x;
    if (i < n) rank[i] = atomicAdd(&deg[dst[i]], 1);
}

__global__ __launch_bounds__(1024) void scanA_kernel(
    const int* __restrict__ deg, int* __restrict__ bsum, int n) {
    __shared__ int s[1024];
    const int tid = threadIdx.x;
    int i = blockIdx.x * 1024 + tid;
    s[tid] = (i < n) ? deg[i] : 0;
    __syncthreads();
    for (int d = 512; d > 0; d >>= 1) {
        if (tid < d) s[tid] += s[tid + d];
        __syncthreads();
    }
    if (tid == 0) bsum[blockIdx.x] = s[0];
}

__global__ __launch_bounds__(1024) void scanC_kernel(
    const int* __restrict__ deg, const int* __restrict__ bsum,
    int* __restrict__ off, int n) {
    __shared__ int s[1024];
    __shared__ int bpref;
    const int tid = threadIdx.x;
    if (tid == 0) {
        int p = 0;
        for (int j = 0; j < blockIdx.x; ++j) p += bsum[j];
        bpref = p;
    }
    const int i = blockIdx.x * 1024 + tid;
    const int v = (i < n) ? deg[i] : 0;
    s[tid] = v;
    __syncthreads();
    for (int d = 1; d < 1024; d <<= 1) {
        int t = (tid >= d) ? s[tid - d] : 0;
        __syncthreads();
        s[tid] += t;
        __syncthreads();
    }
    const int excl = s[tid] - v + bpref;
    if (i < n) {
        off[i] = excl;
        if (i == n - 1) off[n] = excl + v;
    }
}

// Atomic-free fill: pos precomputed from off + rank.
__global__ void fill_kernel(const int* __restrict__ src,
                            const int* __restrict__ dst,
                            const int* __restrict__ rank,
                            const int* __restrict__ off,
                            unsigned short* __restrict__ nbr, int n) {
    int i = blockIdx.x * blockDim.x + threadIdx.x;
    if (i < n) nbr[off[dst[i]] + rank[i]] = (unsigned short)src[i];
}

// ---------------------------------------------------------------------------
// Fused prep: weight transpose->bf16 [N][K] + x fp32->bf16 + deg zeroing.
// ---------------------------------------------------------------------------
__global__ __launch_bounds__(256) void prep_kernel(
    const float* __restrict__ W1a, const float* __restrict__ W1b,
    const float* __restrict__ W2a, const float* __restrict__ W2b,
    const float* __restrict__ x, unsigned short* __restrict__ W1aT,
    unsigned short* __restrict__ W1bT, unsigned short* __restrict__ W2aT,
    unsigned short* __restrict__ W2bT, unsigned short* __restrict__ xb,
    int* __restrict__ deg) {
    int i = blockIdx.x * 256 + threadIdx.x;
    if (i < 8192) {                       // W1a [64][128] -> [128][64]
        int n = i >> 6, k = i & 63;
        W1aT[i] = f2b(W1a[k * 128 + n]);
    } else if (i < 24576) {               // W1b [128][128] -> [128][128]
        int j = i - 8192, n = j >> 7, k = j & 127;
        W1bT[j] = f2b(W1b[k * 128 + n]);
    } else if (i < 40960) {               // W2a [128][128] -> [128][128]
        int j = i - 24576, n = j >> 7, k = j & 127;
        W2aT[j] = f2b(W2a[k * 128 + n]);
    } else if (i < 49152) {               // W2b [128][64] -> [64][128]
        int j = i - 40960, n = j >> 7, k = j & 127;
        W2bT[j] = f2b(W2b[k * 64 + n]);
    } else if (i < 49152 + N_NODES * 16) {  // x convert: float4 -> 4x bf16
        int j = i - 49152;
        float4 v = ((const float4*)x)[j];
        uint2 o;
        o.x = pk(v.x, v.y);
        o.y = pk(v.z, v.w);
        ((uint2*)xb)[j] = o;
    } else {                              // zero deg
        int j = i - (49152 + N_NODES * 16);
        if (j < N_NODES) deg[j] = 0;
    }
}

// ---------------------------------------------------------------------------
// XCD-sliced gather (d=64): blocks with blockIdx%8==s handle feature slice s
// (16B of each 128B row) for ALL nodes. Per-XCD line footprint = 50K x 64B =
// 3.2MB < 4MB L2 -> neighbor reads become L2 hits (~3x lower latency than
// LLC). Slot = 4 lanes x 4B; 64 slots/block; unroll x8 for MLP.
// ---------------------------------------------------------------------------
__global__ __launch_bounds__(256) void gather1_kernel(
    const unsigned short* __restrict__ xb, const int* __restrict__ off,
    const unsigned short* __restrict__ nbr, unsigned short* __restrict__ t1,
    int n_nodes) {
    const int s = blockIdx.x & 7;
    const int tid = threadIdx.x;
    const int node = (blockIdx.x >> 3) * 64 + (tid >> 2);
    const int c = tid & 3;
    if (node >= n_nodes) return;
    const unsigned int* xr = (const unsigned int*)xb;  // row = 32 uints
    const int base = s * 4 + c;
    const unsigned int a = xr[(size_t)node * 32 + base];
    float f0 = blo(a), f1 = bhi(a);
    const int lo = off[node], hi = off[node + 1];
    int j = lo;
    for (; j + 8 <= hi; j += 8) {
        const int n0 = nbr[j], n1 = nbr[j + 1], n2 = nbr[j + 2],
                  n3 = nbr[j + 3], n4 = nbr[j + 4], n5 = nbr[j + 5],
                  n6 = nbr[j + 6], n7 = nbr[j + 7];
        const unsigned int u0 = xr[(size_t)n0 * 32 + base];
        const unsigned int u1 = xr[(size_t)n1 * 32 + base];
        const unsigned int u2 = xr[(size_t)n2 * 32 + base];
        const unsigned int u3 = xr[(size_t)n3 * 32 + base];
        const unsigned int u4 = xr[(size_t)n4 * 32 + base];
        const unsigned int u5 = xr[(size_t)n5 * 32 + base];
        const unsigned int u6 = xr[(size_t)n6 * 32 + base];
        const unsigned int u7 = xr[(size_t)n7 * 32 + base];
        f0 += ((blo(u0) + blo(u1)) + (blo(u2) + blo(u3))) +
              ((blo(u4) + blo(u5)) + (blo(u6) + blo(u7)));
        f1 += ((bhi(u0) + bhi(u1)) + (bhi(u2) + bhi(u3))) +
              ((bhi(u4) + bhi(u5)) + (bhi(u6) + bhi(u7)));
    }
    for (; j < hi; ++j) {
        const unsigned int u = xr[(size_t)nbr[j] * 32 + base];
        f0 += blo(u);
        f1 += bhi(u);
    }
    ((unsigned int*)t1)[(size_t)node * 32 + base] = pk(f0, f1);
}

// XCD-sliced gather (d=128): slice = 32B of each 256B row; slot = 8 lanes;
// 32 slots/block. Per-XCD footprint 3.2MB < 4MB L2.
__global__ __launch_bounds__(256) void gather2_kernel(
    const unsigned short* __restrict__ h, const int* __restrict__ off,
    const unsigned short* __restrict__ nbr, unsigned short* __restrict__ t2,
    int n_nodes) {
    const int s = blockIdx.x & 7;
    const int tid = threadIdx.x;
    const int node = (blockIdx.x >> 3) * 32 + (tid >> 3);
    const int c = tid & 7;
    if (node >= n_nodes) return;
    const unsigned int* hr = (const unsigned int*)h;  // row = 64 uints
    const int base = s * 8 + c;
    const unsigned int a = hr[(size_t)node * 64 + base];
    float f0 = blo(a), f1 = bhi(a);
    const int lo = off[node], hi = off[node + 1];
    int j = lo;
    for (; j + 8 <= hi; j += 8) {
        const int n0 = nbr[j], n1 = nbr[j + 1], n2 = nbr[j + 2],
                  n3 = nbr[j + 3], n4 = nbr[j + 4], n5 = nbr[j + 5],
                  n6 = nbr[j + 6], n7 = nbr[j + 7];
        const unsigned int u0 = hr[(size_t)n0 * 64 + base];
        const unsigned int u1 = hr[(size_t)n1 * 64 + base];
        const unsigned int u2 = hr[(size_t)n2 * 64 + base];
        const unsigned int u3 = hr[(size_t)n3 * 64 + base];
        const unsigned int u4 = hr[(size_t)n4 * 64 + base];
        const unsigned int u5 = hr[(size_t)n5 * 64 + base];
        const unsigned int u6 = hr[(size_t)n6 * 64 + base];
        const unsigned int u7 = hr[(size_t)n7 * 64 + base];
        f0 += ((blo(u0) + blo(u1)) + (blo(u2) + blo(u3))) +
              ((blo(u4) + blo(u5)) + (blo(u6) + blo(u7)));
        f1 += ((bhi(u0) + bhi(u1)) + (bhi(u2) + bhi(u3))) +
              ((bhi(u4) + bhi(u5)) + (bhi(u6) + bhi(u7)));
    }
    for (; j < hi; ++j) {
        const unsigned int u = hr[(size_t)nbr[j] * 64 + base];
        f0 += blo(u);
        f1 += bhi(u);
    }
    ((unsigned int*)t2)[(size_t)node * 64 + base] = pk(f0, f1);
}

// ---------------------------------------------------------------------------
// 2-layer MLP via MFMA 16x16x32 bf16, fp32 accumulate (round-4 verified).
//   out = relu( relu(T @ Wa + ba) @ Wb + bb )
// Block = 256 thr (4 waves), 64 rows; wave w owns rows [w*16, w*16+16).
// C/D layout: col=lane&15, row=quad*4+reg. No barrier between phases (each
// wave reads back only its own hidden strip).
// ---------------------------------------------------------------------------
template <int DIN, int DH, int DOUT, bool OUT_BF16>
__global__ __launch_bounds__(256) void mlp_mfma_kernel(
    const unsigned short* __restrict__ t, const unsigned short* __restrict__ WaT,
    const float* __restrict__ ba, const unsigned short* __restrict__ WbT,
    const float* __restrict__ bb, void* __restrict__ outp, int n_rows) {
    constexpr int SA = DIN + 16;
    constexpr int SH = DH + 16;
    __shared__ unsigned short tA[64 * SA];
    __shared__ unsigned short hidA[64 * SH];

    const int tid = threadIdx.x;
    const int row0 = blockIdx.x * 64;

    constexpr int CHUNKS = 64 * DIN / 8;
    const uint4* tg = (const uint4*)t;
    for (int i = tid; i < CHUNKS; i += 256) {
        const int row = i / (DIN / 8);
        const int cb = i % (DIN / 8);
        uint4 v = {0u, 0u, 0u, 0u};
        const int gr = row0 + row;
        if (gr < n_rows) v = tg[(size_t)gr * (DIN / 8) + cb];
        *(uint4*)&tA[row * SA + cb * 8] = v;
    }
    __syncthreads();

    const int lane = tid & 63;
    const int wv = tid >> 6;
    const int quad = lane >> 4;
    const int l16 = lane & 15;
    const int m0 = wv * 16;

    short8 a1[DIN / 32];
#pragma unroll
    for (int kk = 0; kk < DIN / 32; ++kk)
        a1[kk] = *(const short8*)&tA[(m0 + l16) * SA + kk * 32 + quad * 8];
#pragma unroll
    for (int nt = 0; nt < DH / 16; ++nt) {
        floatx4 acc = {0.f, 0.f, 0.f, 0.f};
#pragma unroll
        for (int kk = 0; kk < DIN / 32; ++kk) {
            short8 b =
                *(const short8*)&WaT[(nt * 16 + l16) * DIN + kk * 32 + quad * 8];
            acc = __builtin_amdgcn_mfma_f32_16x16x32_bf16(a1[kk], b, acc, 0, 0, 0);
        }
        const float bias = ba[nt * 16 + l16];
#pragma unroll
        for (int r = 0; r < 4; ++r) {
            const float v = fmaxf(acc[r] + bias, 0.f);
            hidA[(m0 + quad * 4 + r) * SH + nt * 16 + l16] = f2b(v);
        }
    }

    short8 a2[DH / 32];
#pragma unroll
    for (int kk = 0; kk < DH / 32; ++kk)
        a2[kk] = *(const short8*)&hidA[(m0 + l16) * SH + kk * 32 + quad * 8];
#pragma unroll
    for (int nt = 0; nt < DOUT / 16; ++nt) {
        floatx4 acc = {0.f, 0.f, 0.f, 0.f};
#pragma unroll
        for (int kk = 0; kk < DH / 32; ++kk) {
            short8 b =
                *(const short8*)&WbT[(nt * 16 + l16) * DH + kk * 32 + quad * 8];
            acc = __builtin_amdgcn_mfma_f32_16x16x32_bf16(a2[kk], b, acc, 0, 0, 0);
        }
        const float bias = bb[nt * 16 + l16];
#pragma unroll
        for (int r = 0; r < 4; ++r) {
            const float v = fmaxf(acc[r] + bias, 0.f);
            const int grow = row0 + m0 + quad * 4 + r;
            if (grow < n_rows) {
                if (OUT_BF16)
                    ((unsigned short*)outp)[(size_t)grow * DOUT + nt * 16 + l16] =
                        f2b(v);
                else
                    ((float*)outp)[(size_t)grow * DOUT + nt * 16 + l16] = v;
            }
        }
    }
}

extern "C" void kernel_launch(void* const* d_in, const int* in_sizes, int n_in,
                              void* d_out, int out_size, void* d_ws,
                              size_t ws_size, hipStream_t stream) {
    const float* x   = (const float*)d_in[0];
    const int*   ei  = (const int*)d_in[1];  // [2, N_EDGES] int32
    const float* W1a = (const float*)d_in[2];
    const float* b1a = (const float*)d_in[3];
    const float* W1b = (const float*)d_in[4];
    const float* b1b = (const float*)d_in[5];
    const float* W2a = (const float*)d_in[6];
    const float* b2a = (const float*)d_in[7];
    const float* W2b = (const float*)d_in[8];
    const float* b2b = (const float*)d_in[9];
    float* out = (float*)d_out;

    const int* src = ei;
    const int* dst = ei + N_EDGES;

    // Workspace: bf16 xb[N,64] t1[N,64] h[N,128] t2[N,128] | bf16 weightsT |
    //            int deg/off/bsum/rank | ushort nbr[E]
    unsigned short* xb = (unsigned short*)d_ws;
    unsigned short* t1 = xb + (size_t)N_NODES * 64;
    unsigned short* h  = t1 + (size_t)N_NODES * 64;
    unsigned short* t2 = h + (size_t)N_NODES * 128;
    unsigned short* W1aT = t2 + (size_t)N_NODES * 128;
    unsigned short* W1bT = W1aT + 8192;
    unsigned short* W2aT = W1bT + 16384;
    unsigned short* W2bT = W2aT + 16384;
    int* deg  = (int*)(W2bT + 8192);
    int* off  = deg + N_NODES;
    int* bsum = off + N_NODES + 1;
    int* rank = bsum + 64;
    unsigned short* nbr = (unsigned short*)(rank + N_EDGES);

    constexpr int NB = (N_NODES + 1023) / 1024;  // 49 scan blocks
    constexpr int PREP_THREADS = 49152 + N_NODES * 16 + N_NODES;

    // ---- Prep (weights + x convert + deg zero) ----
    prep_kernel<<<(PREP_THREADS + 255) / 256, 256, 0, stream>>>(
        W1a, W1b, W2a, W2b, x, W1aT, W1bT, W2aT, W2bT, xb, deg);

    // ---- CSR build ----
    hist_rank_kernel<<<(N_EDGES + 255) / 256, 256, 0, stream>>>(dst, deg, rank,
                                                                N_EDGES);
    scanA_kernel<<<NB, 1024, 0, stream>>>(deg, bsum, N_NODES);
    scanC_kernel<<<NB, 1024, 0, stream>>>(deg, bsum, off, N_NODES);
    fill_kernel<<<(N_EDGES + 255) / 256, 256, 0, stream>>>(src, dst, rank, off,
                                                           nbr, N_EDGES);

    // ---- Layer 1 (sliced gather: 8 slices x ceil(N/64) blocks) ----
    gather1_kernel<<<((N_NODES + 63) / 64) * 8, 256, 0, stream>>>(
        xb, off, nbr, t1, N_NODES);
    mlp_mfma_kernel<64, 128, 128, true>
        <<<(N_NODES + 63) / 64, 256, 0, stream>>>(t1, W1aT, b1a, W1bT, b1b, h,
                                                  N_NODES);

    // ---- Layer 2 (sliced gather: 8 slices x ceil(N/32) blocks) ----
    gather2_kernel<<<((N_NODES + 31) / 32) * 8, 256, 0, stream>>>(
        h, off, nbr, t2, N_NODES);
    mlp_mfma_kernel<128, 128, 64, false>
        <<<(N_NODES + 63) / 64, 256, 0, stream>>>(t2, W2aT, b2a, W2bT, b2b, out,
                                                  N_NODES);
}

// Round 12
// 241.434 us; speedup vs baseline: 1.3556x; 1.3556x over previous
//
#include <hip/hip_runtime.h>

#define N_NODES 50000
#define N_EDGES 800000

typedef __attribute__((ext_vector_type(8))) short short8;
typedef __attribute__((ext_vector_type(4))) float floatx4;

// float -> bf16 bits, round-to-nearest-even
static __device__ __forceinline__ unsigned short f2b(float f) {
    unsigned int u = __float_as_uint(f);
    unsigned int r = u + 0x7fffu + ((u >> 16) & 1u);
    return (unsigned short)(r >> 16);
}
static __device__ __forceinline__ unsigned int pk(float a, float b) {
    return (unsigned)f2b(a) | ((unsigned)f2b(b) << 16);
}
static __device__ __forceinline__ float blo(unsigned int u) {
    return __uint_as_float(u << 16);
}
static __device__ __forceinline__ float bhi(unsigned int u) {
    return __uint_as_float(u & 0xffff0000u);
}

// ---------------------------------------------------------------------------
// Fused prep + hist_rank: weight transpose->bf16 [N][K], x fp32->bf16, AND
// the deg histogram + per-edge rank (atomicAdd return value). deg is zeroed
// by a hipMemsetAsync BEFORE this dispatch, so all phases are independent.
// ---------------------------------------------------------------------------
__global__ __launch_bounds__(256) void prep_hist_kernel(
    const float* __restrict__ W1a, const float* __restrict__ W1b,
    const float* __restrict__ W2a, const float* __restrict__ W2b,
    const float* __restrict__ x, const int* __restrict__ dst,
    unsigned short* __restrict__ W1aT, unsigned short* __restrict__ W1bT,
    unsigned short* __restrict__ W2aT, unsigned short* __restrict__ W2bT,
    unsigned short* __restrict__ xb, int* __restrict__ deg,
    int* __restrict__ rank) {
    int i = blockIdx.x * 256 + threadIdx.x;
    if (i < 8192) {                       // W1a [64][128] -> [128][64]
        int n = i >> 6, k = i & 63;
        W1aT[i] = f2b(W1a[k * 128 + n]);
    } else if (i < 24576) {               // W1b [128][128] -> [128][128]
        int j = i - 8192, n = j >> 7, k = j & 127;
        W1bT[j] = f2b(W1b[k * 128 + n]);
    } else if (i < 40960) {               // W2a [128][128] -> [128][128]
        int j = i - 24576, n = j >> 7, k = j & 127;
        W2aT[j] = f2b(W2a[k * 128 + n]);
    } else if (i < 49152) {               // W2b [128][64] -> [64][128]
        int j = i - 40960, n = j >> 7, k = j & 127;
        W2bT[j] = f2b(W2b[k * 64 + n]);
    } else if (i < 49152 + N_NODES * 16) {  // x convert: float4 -> 4x bf16
        int j = i - 49152;
        float4 v = ((const float4*)x)[j];
        uint2 o;
        o.x = pk(v.x, v.y);
        o.y = pk(v.z, v.w);
        ((uint2*)xb)[j] = o;
    } else {                              // histogram + rank
        int e = i - (49152 + N_NODES * 16);
        if (e < N_EDGES) rank[e] = atomicAdd(&deg[dst[e]], 1);
    }
}

__global__ __launch_bounds__(1024) void scanA_kernel(
    const int* __restrict__ deg, int* __restrict__ bsum, int n) {
    __shared__ int s[1024];
    const int tid = threadIdx.x;
    int i = blockIdx.x * 1024 + tid;
    s[tid] = (i < n) ? deg[i] : 0;
    __syncthreads();
    for (int d = 512; d > 0; d >>= 1) {
        if (tid < d) s[tid] += s[tid + d];
        __syncthreads();
    }
    if (tid == 0) bsum[blockIdx.x] = s[0];
}

// In-block exclusive scan + serial 49-entry block prefix.
__global__ __launch_bounds__(1024) void scanC_kernel(
    const int* __restrict__ deg, const int* __restrict__ bsum,
    int* __restrict__ off, int n) {
    __shared__ int s[1024];
    __shared__ int bpref;
    const int tid = threadIdx.x;
    if (tid == 0) {
        int p = 0;
        for (int j = 0; j < blockIdx.x; ++j) p += bsum[j];
        bpref = p;
    }
    const int i = blockIdx.x * 1024 + tid;
    const int v = (i < n) ? deg[i] : 0;
    s[tid] = v;
    __syncthreads();
    for (int d = 1; d < 1024; d <<= 1) {
        int t = (tid >= d) ? s[tid - d] : 0;
        __syncthreads();
        s[tid] += t;
        __syncthreads();
    }
    const int excl = s[tid] - v + bpref;
    if (i < n) {
        off[i] = excl;
        if (i == n - 1) off[n] = excl + v;
    }
}

// Atomic-free fill: pos precomputed from off + rank.
__global__ void fill_kernel(const int* __restrict__ src,
                            const int* __restrict__ dst,
                            const int* __restrict__ rank,
                            const int* __restrict__ off,
                            unsigned short* __restrict__ nbr, int n) {
    int i = blockIdx.x * blockDim.x + threadIdx.x;
    if (i < n) nbr[off[dst[i]] + rank[i]] = (unsigned short)src[i];
}

// ---------------------------------------------------------------------------
// Wave-per-node gather (d=64): whole 64-lane wave works one node. 8 subgroups
// of 8 lanes each load one 16B chunk of a different neighbor row -> 8 edges
// per iteration, wave time = deg/8 (no max-of-k degree divergence; the
// degree branch is wave-uniform). x2 unroll -> 16 rows in flight per wave.
// Final: 3-step __shfl_xor reduction across subgroups; lanes 0..7 write.
// ---------------------------------------------------------------------------
__global__ __launch_bounds__(256) void gather1_kernel(
    const unsigned short* __restrict__ xb, const int* __restrict__ off,
    const unsigned short* __restrict__ nbr, unsigned short* __restrict__ t1,
    int n_nodes) {
    const int tid = threadIdx.x;
    const int lane = tid & 63;
    const int node = blockIdx.x * 4 + (tid >> 6);
    if (node >= n_nodes) return;
    const int sub = lane >> 3;  // 0..7
    const int c = lane & 7;     // 16B chunk within 128B row
    const uint4* xr = (const uint4*)xb;  // row = 8 uint4
    float f0, f1, f2, f3, f4, f5, f6, f7;
    {
        const uint4 a = xr[(size_t)node * 8 + c];
        const float z = (sub == 0) ? 1.0f : 0.0f;  // only sub 0 seeds self-row
        f0 = z * blo(a.x); f1 = z * bhi(a.x);
        f2 = z * blo(a.y); f3 = z * bhi(a.y);
        f4 = z * blo(a.z); f5 = z * bhi(a.z);
        f6 = z * blo(a.w); f7 = z * bhi(a.w);
    }
    const int lo = off[node], hi = off[node + 1];
    int j = lo + sub;
    for (; j + 8 < hi; j += 16) {
        const int n0 = nbr[j];
        const int n1 = nbr[j + 8];
        const uint4 v0 = xr[(size_t)n0 * 8 + c];
        const uint4 v1 = xr[(size_t)n1 * 8 + c];
        f0 += blo(v0.x) + blo(v1.x); f1 += bhi(v0.x) + bhi(v1.x);
        f2 += blo(v0.y) + blo(v1.y); f3 += bhi(v0.y) + bhi(v1.y);
        f4 += blo(v0.z) + blo(v1.z); f5 += bhi(v0.z) + bhi(v1.z);
        f6 += blo(v0.w) + blo(v1.w); f7 += bhi(v0.w) + bhi(v1.w);
    }
    if (j < hi) {
        const uint4 v = xr[(size_t)nbr[j] * 8 + c];
        f0 += blo(v.x); f1 += bhi(v.x); f2 += blo(v.y); f3 += bhi(v.y);
        f4 += blo(v.z); f5 += bhi(v.z); f6 += blo(v.w); f7 += bhi(v.w);
    }
#pragma unroll
    for (int m = 8; m <= 32; m <<= 1) {
        f0 += __shfl_xor(f0, m, 64); f1 += __shfl_xor(f1, m, 64);
        f2 += __shfl_xor(f2, m, 64); f3 += __shfl_xor(f3, m, 64);
        f4 += __shfl_xor(f4, m, 64); f5 += __shfl_xor(f5, m, 64);
        f6 += __shfl_xor(f6, m, 64); f7 += __shfl_xor(f7, m, 64);
    }
    if (sub == 0) {
        uint4 o;
        o.x = pk(f0, f1); o.y = pk(f2, f3);
        o.z = pk(f4, f5); o.w = pk(f6, f7);
        ((uint4*)t1)[(size_t)node * 8 + c] = o;
    }
}

// Wave-per-node gather (d=128): 4 subgroups of 16 lanes, 4 edges/iter,
// x2 unroll -> 8 rows in flight; 2-step __shfl_xor reduce; lanes 0..15 write.
__global__ __launch_bounds__(256) void gather2_kernel(
    const unsigned short* __restrict__ h, const int* __restrict__ off,
    const unsigned short* __restrict__ nbr, unsigned short* __restrict__ t2,
    int n_nodes) {
    const int tid = threadIdx.x;
    const int lane = tid & 63;
    const int node = blockIdx.x * 4 + (tid >> 6);
    if (node >= n_nodes) return;
    const int sub = lane >> 4;  // 0..3
    const int c = lane & 15;    // 16B chunk within 256B row
    const uint4* hr = (const uint4*)h;  // row = 16 uint4
    float f0, f1, f2, f3, f4, f5, f6, f7;
    {
        const uint4 a = hr[(size_t)node * 16 + c];
        const float z = (sub == 0) ? 1.0f : 0.0f;
        f0 = z * blo(a.x); f1 = z * bhi(a.x);
        f2 = z * blo(a.y); f3 = z * bhi(a.y);
        f4 = z * blo(a.z); f5 = z * bhi(a.z);
        f6 = z * blo(a.w); f7 = z * bhi(a.w);
    }
    const int lo = off[node], hi = off[node + 1];
    int j = lo + sub;
    for (; j + 4 < hi; j += 8) {
        const int n0 = nbr[j];
        const int n1 = nbr[j + 4];
        const uint4 v0 = hr[(size_t)n0 * 16 + c];
        const uint4 v1 = hr[(size_t)n1 * 16 + c];
        f0 += blo(v0.x) + blo(v1.x); f1 += bhi(v0.x) + bhi(v1.x);
        f2 += blo(v0.y) + blo(v1.y); f3 += bhi(v0.y) + bhi(v1.y);
        f4 += blo(v0.z) + blo(v1.z); f5 += bhi(v0.z) + bhi(v1.z);
        f6 += blo(v0.w) + blo(v1.w); f7 += bhi(v0.w) + bhi(v1.w);
    }
    if (j < hi) {
        const uint4 v = hr[(size_t)nbr[j] * 16 + c];
        f0 += blo(v.x); f1 += bhi(v.x); f2 += blo(v.y); f3 += bhi(v.y);
        f4 += blo(v.z); f5 += bhi(v.z); f6 += blo(v.w); f7 += bhi(v.w);
    }
#pragma unroll
    for (int m = 16; m <= 32; m <<= 1) {
        f0 += __shfl_xor(f0, m, 64); f1 += __shfl_xor(f1, m, 64);
        f2 += __shfl_xor(f2, m, 64); f3 += __shfl_xor(f3, m, 64);
        f4 += __shfl_xor(f4, m, 64); f5 += __shfl_xor(f5, m, 64);
        f6 += __shfl_xor(f6, m, 64); f7 += __shfl_xor(f7, m, 64);
    }
    if (sub == 0) {
        uint4 o;
        o.x = pk(f0, f1); o.y = pk(f2, f3);
        o.z = pk(f4, f5); o.w = pk(f6, f7);
        ((uint4*)t2)[(size_t)node * 16 + c] = o;
    }
}

// ---------------------------------------------------------------------------
// 2-layer MLP via MFMA 16x16x32 bf16, fp32 accumulate (round-4 verified).
//   out = relu( relu(T @ Wa + ba) @ Wb + bb )
// Block = 256 thr (4 waves), 64 rows; wave w owns rows [w*16, w*16+16).
// C/D layout: col=lane&15, row=quad*4+reg. No barrier between phases (each
// wave reads back only its own hidden strip).
// ---------------------------------------------------------------------------
template <int DIN, int DH, int DOUT, bool OUT_BF16>
__global__ __launch_bounds__(256) void mlp_mfma_kernel(
    const unsigned short* __restrict__ t, const unsigned short* __restrict__ WaT,
    const float* __restrict__ ba, const unsigned short* __restrict__ WbT,
    const float* __restrict__ bb, void* __restrict__ outp, int n_rows) {
    constexpr int SA = DIN + 16;
    constexpr int SH = DH + 16;
    __shared__ unsigned short tA[64 * SA];
    __shared__ unsigned short hidA[64 * SH];

    const int tid = threadIdx.x;
    const int row0 = blockIdx.x * 64;

    constexpr int CHUNKS = 64 * DIN / 8;
    const uint4* tg = (const uint4*)t;
    for (int i = tid; i < CHUNKS; i += 256) {
        const int row = i / (DIN / 8);
        const int cb = i % (DIN / 8);
        uint4 v = {0u, 0u, 0u, 0u};
        const int gr = row0 + row;
        if (gr < n_rows) v = tg[(size_t)gr * (DIN / 8) + cb];
        *(uint4*)&tA[row * SA + cb * 8] = v;
    }
    __syncthreads();

    const int lane = tid & 63;
    const int wv = tid >> 6;
    const int quad = lane >> 4;
    const int l16 = lane & 15;
    const int m0 = wv * 16;

    short8 a1[DIN / 32];
#pragma unroll
    for (int kk = 0; kk < DIN / 32; ++kk)
        a1[kk] = *(const short8*)&tA[(m0 + l16) * SA + kk * 32 + quad * 8];
#pragma unroll
    for (int nt = 0; nt < DH / 16; ++nt) {
        floatx4 acc = {0.f, 0.f, 0.f, 0.f};
#pragma unroll
        for (int kk = 0; kk < DIN / 32; ++kk) {
            short8 b =
                *(const short8*)&WaT[(nt * 16 + l16) * DIN + kk * 32 + quad * 8];
            acc = __builtin_amdgcn_mfma_f32_16x16x32_bf16(a1[kk], b, acc, 0, 0, 0);
        }
        const float bias = ba[nt * 16 + l16];
#pragma unroll
        for (int r = 0; r < 4; ++r) {
            const float v = fmaxf(acc[r] + bias, 0.f);
            hidA[(m0 + quad * 4 + r) * SH + nt * 16 + l16] = f2b(v);
        }
    }

    short8 a2[DH / 32];
#pragma unroll
    for (int kk = 0; kk < DH / 32; ++kk)
        a2[kk] = *(const short8*)&hidA[(m0 + l16) * SH + kk * 32 + quad * 8];
#pragma unroll
    for (int nt = 0; nt < DOUT / 16; ++nt) {
        floatx4 acc = {0.f, 0.f, 0.f, 0.f};
#pragma unroll
        for (int kk = 0; kk < DH / 32; ++kk) {
            short8 b =
                *(const short8*)&WbT[(nt * 16 + l16) * DH + kk * 32 + quad * 8];
            acc = __builtin_amdgcn_mfma_f32_16x16x32_bf16(a2[kk], b, acc, 0, 0, 0);
        }
        const float bias = bb[nt * 16 + l16];
#pragma unroll
        for (int r = 0; r < 4; ++r) {
            const float v = fmaxf(acc[r] + bias, 0.f);
            const int grow = row0 + m0 + quad * 4 + r;
            if (grow < n_rows) {
                if (OUT_BF16)
                    ((unsigned short*)outp)[(size_t)grow * DOUT + nt * 16 + l16] =
                        f2b(v);
                else
                    ((float*)outp)[(size_t)grow * DOUT + nt * 16 + l16] = v;
            }
        }
    }
}

extern "C" void kernel_launch(void* const* d_in, const int* in_sizes, int n_in,
                              void* d_out, int out_size, void* d_ws,
                              size_t ws_size, hipStream_t stream) {
    const float* x   = (const float*)d_in[0];
    const int*   ei  = (const int*)d_in[1];  // [2, N_EDGES] int32
    const float* W1a = (const float*)d_in[2];
    const float* b1a = (const float*)d_in[3];
    const float* W1b = (const float*)d_in[4];
    const float* b1b = (const float*)d_in[5];
    const float* W2a = (const float*)d_in[6];
    const float* b2a = (const float*)d_in[7];
    const float* W2b = (const float*)d_in[8];
    const float* b2b = (const float*)d_in[9];
    float* out = (float*)d_out;

    const int* src = ei;
    const int* dst = ei + N_EDGES;

    // Workspace: bf16 xb[N,64] t1[N,64] h[N,128] t2[N,128] | bf16 weightsT |
    //            int deg/off/bsum/rank | ushort nbr[E]
    unsigned short* xb = (unsigned short*)d_ws;
    unsigned short* t1 = xb + (size_t)N_NODES * 64;
    unsigned short* h  = t1 + (size_t)N_NODES * 64;
    unsigned short* t2 = h + (size_t)N_NODES * 128;
    unsigned short* W1aT = t2 + (size_t)N_NODES * 128;
    unsigned short* W1bT = W1aT + 8192;
    unsigned short* W2aT = W1bT + 16384;
    unsigned short* W2bT = W2aT + 16384;
    int* deg  = (int*)(W2bT + 8192);
    int* off  = deg + N_NODES;
    int* bsum = off + N_NODES + 1;
    int* rank = bsum + 64;
    unsigned short* nbr = (unsigned short*)(rank + N_EDGES);

    constexpr int NB = (N_NODES + 1023) / 1024;  // 49 scan blocks
    constexpr int PREP_THREADS = 49152 + N_NODES * 16 + N_EDGES;

    // ---- Prep + hist (deg zeroed first; memset is cheap + async) ----
    hipMemsetAsync(deg, 0, N_NODES * sizeof(int), stream);
    prep_hist_kernel<<<(PREP_THREADS + 255) / 256, 256, 0, stream>>>(
        W1a, W1b, W2a, W2b, x, dst, W1aT, W1bT, W2aT, W2bT, xb, deg, rank);

    // ---- CSR build ----
    scanA_kernel<<<NB, 1024, 0, stream>>>(deg, bsum, N_NODES);
    scanC_kernel<<<NB, 1024, 0, stream>>>(deg, bsum, off, N_NODES);
    fill_kernel<<<(N_EDGES + 255) / 256, 256, 0, stream>>>(src, dst, rank, off,
                                                           nbr, N_EDGES);

    // ---- Layer 1 (wave-per-node gathers: 4 nodes/block) ----
    gather1_kernel<<<(N_NODES + 3) / 4, 256, 0, stream>>>(xb, off, nbr, t1,
                                                          N_NODES);
    mlp_mfma_kernel<64, 128, 128, true>
        <<<(N_NODES + 63) / 64, 256, 0, stream>>>(t1, W1aT, b1a, W1bT, b1b, h,
                                                  N_NODES);

    // ---- Layer 2 ----
    gather2_kernel<<<(N_NODES + 3) / 4, 256, 0, stream>>>(h, off, nbr, t2,
                                                          N_NODES);
    mlp_mfma_kernel<128, 128, 64, false>
        <<<(N_NODES + 63) / 64, 256, 0, stream>>>(t2, W2aT, b2a, W2bT, b2b, out,
                                                  N_NODES);
}